// Round 3
// baseline (223.533 us; speedup 1.0000x reference)
//
#include <hip/hip_runtime.h>

typedef _Float16 half8 __attribute__((ext_vector_type(8)));
typedef _Float16 half4 __attribute__((ext_vector_type(4)));
typedef _Float16 half2v __attribute__((ext_vector_type(2)));
typedef float floatx4 __attribute__((ext_vector_type(4)));

// Problem constants: B=2, N=2048, D=1024, H=16, C=3, Dh=64
// q pre-scaled by 0.125*LOG2E; mask in log2e units -> softmax = exp2(st+m).
// Coord bias -cp[k] folded multiplicatively: V rows scaled by e^{-cp[k]} (fp16,
// matched exactly in the denominator via the esch MFMA operand).
#define LOG2E 1.44269504088896f
#define QSCALE 0.18033688011112f   // 0.125 * LOG2E

__device__ __forceinline__ void async16(const void* g, void* l) {
    __builtin_amdgcn_global_load_lds(
        (const __attribute__((address_space(1))) unsigned int*)g,
        (__attribute__((address_space(3))) unsigned int*)l, 16, 0, 0);
}
__device__ __forceinline__ half4 pack4(float a, float b, float c, float d) {
    half2v lo = __builtin_bit_cast(half2v, __builtin_amdgcn_cvt_pkrtz(a, b));
    half2v hi = __builtin_bit_cast(half2v, __builtin_amdgcn_cvt_pkrtz(c, d));
    half4 r; r[0] = lo[0]; r[1] = lo[1]; r[2] = hi[0]; r[3] = hi[1];
    return r;
}

// ---------------- fused prep: convert_x | transpose_w | escale | prep_mask ----------------
__global__ __launch_bounds__(256) void k_prep(
    const float* __restrict__ x, const float* __restrict__ W,
    const float* __restrict__ coords, const float* __restrict__ rw,
    const float* __restrict__ mask,
    _Float16* __restrict__ xh, _Float16* __restrict__ Wt,
    _Float16* __restrict__ esch, _Float16* __restrict__ maskp) {
    __shared__ float smem[4352];        // 17.4 KB: prep_mask tile 64x68; transpose 32x33
    int bx = blockIdx.x, tid = threadIdx.x;
    if (bx < 2048) {
        // ---- convert x (fp32 -> fp16), 8 elements/thread ----
        int i = bx * 256 + tid;
        const floatx4* xin = (const floatx4*)x;
        floatx4 a = xin[i * 2];
        floatx4 b = xin[i * 2 + 1];
        half8 h;
        h[0] = (_Float16)a[0]; h[1] = (_Float16)a[1]; h[2] = (_Float16)a[2]; h[3] = (_Float16)a[3];
        h[4] = (_Float16)b[0]; h[5] = (_Float16)b[1]; h[6] = (_Float16)b[2]; h[7] = (_Float16)b[3];
        *(half8*)&xh[i * 8] = h;
    } else if (bx < 5120) {
        // ---- transpose + convert Wqkv [1024,3072] -> Wt fp16 [3072,1024] ----
        int b2 = bx - 2048;
        int n0 = (b2 % 96) * 32, k0 = (b2 / 96) * 32;
        int tx = tid & 31, ty = tid >> 5;   // (32,8)
        float (*tile)[33] = (float(*)[33])smem;
        #pragma unroll
        for (int r = 0; r < 4; ++r)
            tile[ty + r * 8][tx] = W[(size_t)(k0 + ty + r * 8) * 3072 + n0 + tx];
        __syncthreads();
        #pragma unroll
        for (int r = 0; r < 4; ++r)
            Wt[(size_t)(n0 + ty + r * 8) * 1024 + k0 + tx] = (_Float16)tile[tx][ty + r * 8];
    } else if (bx < 5376) {
        // ---- esch[b,h,n] = fp16( exp2(-LOG2E * sum_c coords*rw) ) ----
        int idx = (bx - 5120) * 256 + tid;
        int bh = idx >> 11, n = idx & 2047;
        int b = bh >> 4, h = bh & 15;
        const float* c = &coords[(b * 2048 + n) * 3];
        const float* w = &rw[h * 3];
        float v = -LOG2E * (c[0] * w[0] + c[1] * w[1] + c[2] * w[2]);
        esch[idx] = (_Float16)__builtin_amdgcn_exp2f(v);
    } else {
        // ---- mask -> fp16*LOG2E, S^T MFMA C-fragment layout ----
        int bid = bx - 5376;
        int qt = bid >> 5, kt = bid & 31;
        int row0 = qt * 64, col0 = kt * 64;
        int lr = tid >> 2, lc = (tid & 3) * 16;
        #pragma unroll
        for (int j = 0; j < 4; ++j)
            *(floatx4*)&smem[lr * 68 + lc + j * 4] =
                *(const floatx4*)&mask[(size_t)(row0 + lr) * 2048 + col0 + lc + j * 4];
        __syncthreads();
        int w = tid >> 6, lane = tid & 63, quad = lane >> 4, l16 = lane & 15;
        half4* outp = (half4*)maskp + (size_t)((qt * 32 + kt) * 4 + w) * 256 + lane;
        #pragma unroll
        for (int t = 0; t < 4; ++t) {
            floatx4 m = *(const floatx4*)&smem[(w * 16 + l16) * 68 + t * 16 + quad * 4];
            outp[t * 64] = pack4(m[0] * LOG2E, m[1] * LOG2E, m[2] * LOG2E, m[3] * LOG2E);
        }
    }
}

// ---------------- fused QKV GEMM: BK=32, double-buffered async staging ----------------
__global__ __launch_bounds__(256) void k_gemm(
    const _Float16* __restrict__ Ah, const _Float16* __restrict__ Bt,
    const float* __restrict__ bias, const _Float16* __restrict__ esch,
    _Float16* __restrict__ qh, _Float16* __restrict__ kh, _Float16* __restrict__ vt) {
    __shared__ _Float16 smem[16384];   // 2 bufs x (As 4096 + Bs 4096) halves = 32 KB
    int tid = threadIdx.x;
    int w = tid >> 6, lane = tid & 63;
    int quad = lane >> 4, l16 = lane & 15;
    int m0 = blockIdx.y * 128;
    int n0 = blockIdx.x * 128;
    bool QK = n0 < 2048;
    int mq = (w >> 1) * 64, nq = (w & 1) * 64;
    int c0 = n0 + nq;

    int rl4 = lane >> 2;            // row within 16-row staging chunk
    int pb4 = lane & 3;             // physical 16B block within 64B row
    floatx4 acc[4][4] = {};

    const _Float16* ap[2];
    const _Float16* bp[2];
    #pragma unroll
    for (int j = 0; j < 2; ++j) {
        int row = w * 32 + j * 16 + rl4;
        int lb = pb4 ^ (row & 3) ^ ((row >> 2) & 3);
        ap[j] = Ah + (size_t)(m0 + row) * 1024 + lb * 8;
        bp[j] = Bt + (size_t)(n0 + row) * 1024 + lb * 8;
    }

    #define GSTAGE(buf) {                                      \
        _Float16* As_ = smem + (buf) * 8192;                   \
        _Float16* Bs_ = As_ + 4096;                            \
        async16(ap[0], &As_[(w * 32) * 32]);                   \
        async16(ap[1], &As_[(w * 32 + 16) * 32]);              \
        async16(bp[0], &Bs_[(w * 32) * 32]);                   \
        async16(bp[1], &Bs_[(w * 32 + 16) * 32]);              \
        ap[0] += 32; ap[1] += 32; bp[0] += 32; bp[1] += 32;    \
    }

    #define GBODY(cur, last) {                                                         \
        __syncthreads();                                                               \
        if (!(last)) GSTAGE((cur) ^ 1);                                                \
        const _Float16* As_ = smem + (cur) * 8192;                                     \
        const _Float16* Bs_ = As_ + 4096;                                              \
        half8 af[4], bf[4];                                                            \
        _Pragma("unroll")                                                              \
        for (int s = 0; s < 4; ++s) {                                                  \
            int ra = mq + s * 16 + l16;                                                \
            af[s] = *(const half8*)&As_[ra * 32 +                                      \
                ((quad ^ (ra & 3) ^ ((ra >> 2) & 3)) << 3)];                           \
            int rb = nq + s * 16 + l16;                                                \
            bf[s] = *(const half8*)&Bs_[rb * 32 +                                      \
                ((quad ^ (rb & 3) ^ ((rb >> 2) & 3)) << 3)];                           \
        }                                                                              \
        if (QK) {                                                                      \
            _Pragma("unroll")                                                          \
            for (int ms = 0; ms < 4; ++ms)                                             \
                _Pragma("unroll")                                                      \
                for (int ns = 0; ns < 4; ++ns)                                         \
                    acc[ms][ns] = __builtin_amdgcn_mfma_f32_16x16x32_f16(              \
                        bf[ns], af[ms], acc[ms][ns], 0, 0, 0);                         \
        } else {                                                                       \
            _Pragma("unroll")                                                          \
            for (int ms = 0; ms < 4; ++ms)                                             \
                _Pragma("unroll")                                                      \
                for (int ns = 0; ns < 4; ++ns)                                         \
                    acc[ms][ns] = __builtin_amdgcn_mfma_f32_16x16x32_f16(              \
                        af[ms], bf[ns], acc[ms][ns], 0, 0, 0);                         \
        }                                                                              \
    }

    GSTAGE(0);
    #pragma unroll 1
    for (int kt2 = 0; kt2 < 15; ++kt2) {
        GBODY(0, false);
        GBODY(1, false);
    }
    GBODY(0, false);
    GBODY(1, true);
    #undef GBODY
    #undef GSTAGE

    __syncthreads();   // all waves done reading staging before slab reuse

    // ---- epilogue: wave-private 32x72 slab, 2 passes, coalesced half8 stores ----
    _Float16* Ls = smem + w * 2304;
    int rl = lane >> 3, pb = lane & 7;
    int b = (m0 + mq) >> 11, nbase = (m0 + mq) & 2047;
    if (QK) {
        float qsc = (c0 < 1024) ? QSCALE : 1.0f;    // q heads pre-scaled for softmax
        int h2 = c0 >> 6;                           // 0..31: q heads then k heads
        _Float16* dst = (h2 < 16 ? qh : kh) + (size_t)(((b << 4) + (h2 & 15)) * 2048) * 64;
        int d0 = pb << 3;
        #pragma unroll
        for (int p = 0; p < 2; ++p) {
            #pragma unroll
            for (int ns = 0; ns < 4; ++ns) {
                floatx4 b4 = *(const floatx4*)&bias[c0 + ns * 16 + quad * 4];
                #pragma unroll
                for (int m2 = 0; m2 < 2; ++m2) {
                    int ms = p * 2 + m2;
                    floatx4 v;
                    #pragma unroll
                    for (int i = 0; i < 4; ++i) v[i] = (acc[ms][ns][i] + b4[i]) * qsc;
                    *(half4*)&Ls[(m2 * 16 + l16) * 72 + ns * 16 + quad * 4] =
                        pack4(v[0], v[1], v[2], v[3]);
                }
            }
            #pragma unroll
            for (int rep = 0; rep < 4; ++rep) {
                int nl = rep * 8 + rl;
                half8 v = *(const half8*)&Ls[nl * 72 + d0];
                *(half8*)&dst[(size_t)(nbase + p * 32 + nl) * 64 + d0] = v;
            }
        }
    } else {
        int h = (c0 - 2048) >> 6;
        _Float16* dst = vt + (size_t)(((b << 4) + h) * 64) * 2048;
        // V rows scaled by e^{-cp[b,h,n]} in fp32 (single fp16 rounding, matched
        // bit-exactly with the attention denominator which uses the same fp16 esch).
        const _Float16* ePtr = esch + (size_t)((b << 4) + h) * 2048 + nbase + quad * 4;
        float ef[4][4];
        #pragma unroll
        for (int ms = 0; ms < 4; ++ms) {
            half4 e4 = *(const half4*)&ePtr[ms * 16];
            #pragma unroll
            for (int i = 0; i < 4; ++i) ef[ms][i] = (float)e4[i];
        }
        int noff = pb << 3;
        #pragma unroll
        for (int p = 0; p < 2; ++p) {
            #pragma unroll
            for (int n2 = 0; n2 < 2; ++n2) {
                int ns = p * 2 + n2;
                float bv = bias[c0 + ns * 16 + l16];
                #pragma unroll
                for (int ms = 0; ms < 4; ++ms) {
                    *(half4*)&Ls[(n2 * 16 + l16) * 72 + ms * 16 + quad * 4] =
                        pack4((acc[ms][ns][0] + bv) * ef[ms][0],
                              (acc[ms][ns][1] + bv) * ef[ms][1],
                              (acc[ms][ns][2] + bv) * ef[ms][2],
                              (acc[ms][ns][3] + bv) * ef[ms][3]);
                }
            }
            #pragma unroll
            for (int rep = 0; rep < 4; ++rep) {
                int cl = rep * 8 + rl;
                half8 v = *(const half8*)&Ls[cl * 72 + noff];
                *(half8*)&dst[(size_t)(p * 32 + cl) * 2048 + nbase + noff] = v;
            }
        }
    }
}

// ---------------- flash attention: in-block split-K, 8 waves, 32 q rows/wave ----------------
// 512 blocks (qt2 0..15 x bh 0..31) x 512 threads. Waves 0-3 ("group 0") process
// k-tiles 0..15, waves 4-7 ("group 1") k-tiles 16..31, for the SAME 128 q rows.
// Each group has its own 32 KB K/V double-buffer (64 KB/block -> 2 blocks/CU ->
// 4 waves/SIMD, vs 2 before: doubles phase diversity so MFMA phases of some waves
// overlap exp2/VALU phases of others). Softmax has no running max (pure exp2 sums)
// so partials combine exactly: wave pairs (w, w+4) exchange partial O/l via LDS
// (reusing staging buffers) and split the output stores.
__global__ __launch_bounds__(512, 4) void k_attn(
    const _Float16* __restrict__ qh, const _Float16* __restrict__ kh,
    const _Float16* __restrict__ vt, const _Float16* __restrict__ maskp,
    const _Float16* __restrict__ esch, float* __restrict__ out) {
    __shared__ _Float16 KV[2][2][8192];   // [group][buf]: K [0,4096), V [4096,8192); 64 KB
    int tid = threadIdx.x;
    int w = tid >> 6, lane = tid & 63;
    int g2 = w >> 2, wg = w & 3;          // k-group, wave-within-group
    int quad = lane >> 4, l16 = lane & 15;
    int rl = lane >> 3, pb = lane & 7;
    int bid = blockIdx.x;
    int qt2 = bid & 15, bh = bid >> 4;
    int b = bh >> 4, h = bh & 15;
    int qrow = qt2 * 128 + wg * 32;

    half8 qf[2][2];
    #pragma unroll
    for (int g = 0; g < 2; ++g) {
        const _Float16* qp = &qh[((size_t)bh * 2048 + qrow + g * 16 + l16) * 64];
        qf[g][0] = *(const half8*)&qp[quad * 8];
        qf[g][1] = *(const half8*)&qp[32 + quad * 8];
    }
    floatx4 o0[4] = {}, o1[4] = {};
    floatx4 ol0 = {}, ol1 = {};        // denominator accumulators (esch-weighted)

    int sw = (pb ^ rl) << 3;
    const _Float16* kp0 = kh + (size_t)bh * 131072 + (size_t)(wg * 16 + rl) * 64 + sw
                             + (size_t)g2 * 65536;
    const _Float16* kp1 = kp0 + 512;                 // +8 rows
    const _Float16* vp0 = vt + (size_t)bh * 131072 + (size_t)(wg * 16 + rl) * 2048 + sw
                             + (size_t)g2 * 1024;
    const _Float16* vp1 = vp0 + 16384;               // +8 d-rows
    // mask fragment pointers (old-fragment coords: qt_old = qt2*2 + (wg>>1),
    // w_old = (wg&1)*2 + g, starting k-tile = g2*16)
    const half4* mp0 = (const half4*)maskp +
        ((size_t)(qt2 * 2 + (wg >> 1)) * 128 + (size_t)g2 * 64 + (wg & 1) * 2) * 256 + lane;
    const half4* mp1 = mp0 + 256;
    const _Float16* ep = esch + bh * 2048 + g2 * 1024 + quad * 4;

    // double-buffered prefetch registers for mask/esch
    half4 mA0[4], mA1[4], eA[4];
    half4 mB0[4], mB1[4], eB[4];

    #define STAGE(buf) {                                             \
        async16(kp0, &KV[g2][buf][(wg * 16) * 64]);                  \
        async16(kp1, &KV[g2][buf][(wg * 16 + 8) * 64]);              \
        async16(vp0, &KV[g2][buf][4096 + (wg * 16) * 64]);           \
        async16(vp1, &KV[g2][buf][4096 + (wg * 16 + 8) * 64]);       \
        kp0 += 4096; kp1 += 4096; vp0 += 64; vp1 += 64;              \
    }

    #define MPREF(M0, M1, EV) {                                      \
        _Pragma("unroll")                                            \
        for (int t = 0; t < 4; ++t) M0[t] = mp0[t * 64];             \
        _Pragma("unroll")                                            \
        for (int t = 0; t < 4; ++t) M1[t] = mp1[t * 64];             \
        _Pragma("unroll")                                            \
        for (int t = 0; t < 4; ++t) EV[t] = *(const half4*)&ep[t * 16]; \
        mp0 += 1024; mp1 += 1024; ep += 64;                          \
    }

    #define BODY(cur, last, MC0, MC1, EC, MN0, MN1, EN) {                              \
        __syncthreads();                                                               \
        if (!(last)) { STAGE((cur) ^ 1); MPREF(MN0, MN1, EN); }                        \
        const _Float16* Ksc = &KV[g2][cur][0];                                         \
        const _Float16* Vsc = &KV[g2][cur][4096];                                      \
        half8 kf0[4], kf1[4];                                                          \
        _Pragma("unroll")                                                              \
        for (int t = 0; t < 4; ++t) {                                                  \
            int r = t * 16 + l16;                                                      \
            kf0[t] = *(const half8*)&Ksc[r * 64 + ((quad ^ (r & 7)) << 3)];            \
            kf1[t] = *(const half8*)&Ksc[r * 64 + (((quad + 4) ^ (r & 7)) << 3)];      \
        }                                                                              \
        half4 pt[2][4];                                                                \
        _Pragma("unroll")                                                              \
        for (int t = 0; t < 4; ++t) {                                                  \
            half4 ml = MC0[t];                                                         \
            floatx4 z;                                                                 \
            z[0] = (float)ml[0]; z[1] = (float)ml[1];                                  \
            z[2] = (float)ml[2]; z[3] = (float)ml[3];                                  \
            z = __builtin_amdgcn_mfma_f32_16x16x32_f16(kf0[t], qf[0][0], z, 0, 0, 0);  \
            z = __builtin_amdgcn_mfma_f32_16x16x32_f16(kf1[t], qf[0][1], z, 0, 0, 0);  \
            pt[0][t] = pack4(__builtin_amdgcn_exp2f(z[0]),                             \
                             __builtin_amdgcn_exp2f(z[1]),                             \
                             __builtin_amdgcn_exp2f(z[2]),                             \
                             __builtin_amdgcn_exp2f(z[3]));                            \
        }                                                                              \
        _Pragma("unroll")                                                              \
        for (int t = 0; t < 4; ++t) {                                                  \
            half4 ml = MC1[t];                                                         \
            floatx4 z;                                                                 \
            z[0] = (float)ml[0]; z[1] = (float)ml[1];                                  \
            z[2] = (float)ml[2]; z[3] = (float)ml[3];                                  \
            z = __builtin_amdgcn_mfma_f32_16x16x32_f16(kf0[t], qf[1][0], z, 0, 0, 0);  \
            z = __builtin_amdgcn_mfma_f32_16x16x32_f16(kf1[t], qf[1][1], z, 0, 0, 0);  \
            pt[1][t] = pack4(__builtin_amdgcn_exp2f(z[0]),                             \
                             __builtin_amdgcn_exp2f(z[1]),                             \
                             __builtin_amdgcn_exp2f(z[2]),                             \
                             __builtin_amdgcn_exp2f(z[3]));                            \
        }                                                                              \
        _Pragma("unroll")                                                              \
        for (int t = 0; t < 4; ++t) {                                                  \
            ol0 = __builtin_amdgcn_mfma_f32_16x16x16f16(EC[t], pt[0][t], ol0, 0, 0, 0); \
            ol1 = __builtin_amdgcn_mfma_f32_16x16x16f16(EC[t], pt[1][t], ol1, 0, 0, 0); \
        }                                                                              \
        _Pragma("unroll")                                                              \
        for (int dt = 0; dt < 4; ++dt) {                                               \
            int rv = dt * 16 + l16;                                                    \
            _Pragma("unroll")                                                          \
            for (int t = 0; t < 4; ++t) {                                              \
                half4 vf = *(const half4*)&Vsc[rv * 64 +                               \
                    (((t * 2 + (quad >> 1)) ^ (rv & 7)) << 3) + ((quad & 1) << 2)];    \
                o0[dt] = __builtin_amdgcn_mfma_f32_16x16x16f16(vf, pt[0][t], o0[dt], 0, 0, 0); \
                o1[dt] = __builtin_amdgcn_mfma_f32_16x16x16f16(vf, pt[1][t], o1[dt], 0, 0, 0); \
            }                                                                          \
        }                                                                              \
    }

    STAGE(0);
    MPREF(mA0, mA1, eA);
    #pragma unroll 1
    for (int kt2 = 0; kt2 < 7; ++kt2) {
        BODY(0, false, mA0, mA1, eA, mB0, mB1, eB);
        BODY(1, false, mB0, mB1, eB, mA0, mA1, eA);
    }
    BODY(0, false, mA0, mA1, eA, mB0, mB1, eB);
    BODY(1, true,  mB0, mB1, eB, mA0, mA1, eA);
    #undef BODY
    #undef MPREF
    #undef STAGE

    // ---- combine partials across the wave pair (w, w^4) via LDS ----
    __syncthreads();                       // everyone done reading staging buffers
    float* comb = (float*)KV;              // 8 waves x 17 idx x 64 lanes = 34.8 KB
    {
        float* dst = comb + ((size_t)w * 17) * 64 + lane;
        if (g2 == 0) {                     // group 0 exports o1/ol1 (partner stores rows +16)
            #pragma unroll
            for (int dt = 0; dt < 4; ++dt)
                #pragma unroll
                for (int i = 0; i < 4; ++i)
                    dst[(dt * 4 + i) * 64] = o1[dt][i];
            dst[16 * 64] = ol1[0];
        } else {                           // group 1 exports o0/ol0
            #pragma unroll
            for (int dt = 0; dt < 4; ++dt)
                #pragma unroll
                for (int i = 0; i < 4; ++i)
                    dst[(dt * 4 + i) * 64] = o0[dt][i];
            dst[16 * 64] = ol0[0];
        }
    }
    __syncthreads();
    {
        const float* src = comb + ((size_t)(w ^ 4) * 17) * 64 + lane;
        if (g2 == 0) {
            // sum own o0 with partner's o0 -> store q-group 0 (rows qrow + l16)
            #pragma unroll
            for (int dt = 0; dt < 4; ++dt)
                #pragma unroll
                for (int i = 0; i < 4; ++i)
                    o0[dt][i] += src[(dt * 4 + i) * 64];
            float inv = 1.f / (ol0[0] + src[16 * 64]);
            size_t obase = ((size_t)(b * 2048 + qrow + l16)) * 1024 + h * 64 + quad * 4;
            #pragma unroll
            for (int dt = 0; dt < 4; ++dt) {
                floatx4 r;
                #pragma unroll
                for (int i = 0; i < 4; ++i) r[i] = o0[dt][i] * inv;
                *(floatx4*)&out[obase + dt * 16] = r;
            }
        } else {
            // sum own o1 with partner's o1 -> store q-group 1 (rows qrow + 16 + l16)
            #pragma unroll
            for (int dt = 0; dt < 4; ++dt)
                #pragma unroll
                for (int i = 0; i < 4; ++i)
                    o1[dt][i] += src[(dt * 4 + i) * 64];
            float inv = 1.f / (ol1[0] + src[16 * 64]);
            size_t obase = ((size_t)(b * 2048 + qrow + 16 + l16)) * 1024 + h * 64 + quad * 4;
            #pragma unroll
            for (int dt = 0; dt < 4; ++dt) {
                floatx4 r;
                #pragma unroll
                for (int i = 0; i < 4; ++i) r[i] = o1[dt][i] * inv;
                *(floatx4*)&out[obase + dt * 16] = r;
            }
        }
    }
}

extern "C" void kernel_launch(void* const* d_in, const int* in_sizes, int n_in,
                              void* d_out, int out_size, void* d_ws, size_t ws_size,
                              hipStream_t stream) {
    const float* x      = (const float*)d_in[0];
    const float* coords = (const float*)d_in[1];
    const float* mask   = (const float*)d_in[2];
    const float* Wqkv   = (const float*)d_in[3];
    const float* bqkv   = (const float*)d_in[4];
    const float* rw     = (const float*)d_in[5];
    float* out = (float*)d_out;

    // Workspace layout
    //   xh   : [0,          8,388,608)
    //   maskp: [8,388,608,  16,777,216)
    //   Wt   : [16,777,216, 23,068,672)
    //   qh   : [23,068,672, 31,457,280)
    //   kh   : [31,457,280, 39,845,888)
    //   vt   : [39,845,888, 48,234,496)
    //   esch : [48,234,496, 48,365,568)
    char* ws = (char*)d_ws;
    _Float16* xh    = (_Float16*)(ws);
    _Float16* maskp = (_Float16*)(ws + 8388608);
    _Float16* Wt    = (_Float16*)(ws + 16777216);
    _Float16* qh    = (_Float16*)(ws + 23068672);
    _Float16* kh    = (_Float16*)(ws + 31457280);
    _Float16* vt    = (_Float16*)(ws + 39845888);
    _Float16* esch  = (_Float16*)(ws + 48234496);

    k_prep<<<6400, 256, 0, stream>>>(x, Wqkv, coords, rw, mask, xh, Wt, esch, maskp);
    k_gemm<<<dim3(24, 32), 256, 0, stream>>>(xh, Wt, bqkv, esch, qh, kh, vt);
    k_attn<<<512, 512, 0, stream>>>(qh, kh, vt, maskp, esch, out);
}

// Round 4
// 185.556 us; speedup vs baseline: 1.2047x; 1.2047x over previous
//
#include <hip/hip_runtime.h>

typedef _Float16 half8 __attribute__((ext_vector_type(8)));
typedef _Float16 half4 __attribute__((ext_vector_type(4)));
typedef _Float16 half2v __attribute__((ext_vector_type(2)));
typedef float floatx4 __attribute__((ext_vector_type(4)));

// Problem constants: B=2, N=2048, D=1024, H=16, C=3, Dh=64
// q pre-scaled by 0.125*LOG2E; mask in log2e units -> softmax = exp2(st+m).
// Coord bias -cp[k] folded multiplicatively: V rows scaled by e^{-cp[k]} (fp16,
// matched exactly in the denominator via the esch MFMA operand).
#define LOG2E 1.44269504088896f
#define QSCALE 0.18033688011112f   // 0.125 * LOG2E

__device__ __forceinline__ void async16(const void* g, void* l) {
    __builtin_amdgcn_global_load_lds(
        (const __attribute__((address_space(1))) unsigned int*)g,
        (__attribute__((address_space(3))) unsigned int*)l, 16, 0, 0);
}
__device__ __forceinline__ half4 pack4(float a, float b, float c, float d) {
    half2v lo = __builtin_bit_cast(half2v, __builtin_amdgcn_cvt_pkrtz(a, b));
    half2v hi = __builtin_bit_cast(half2v, __builtin_amdgcn_cvt_pkrtz(c, d));
    half4 r; r[0] = lo[0]; r[1] = lo[1]; r[2] = hi[0]; r[3] = hi[1];
    return r;
}

// ---------------- fused prep: convert_x | transpose_w | escale | prep_mask ----------------
__global__ __launch_bounds__(256) void k_prep(
    const float* __restrict__ x, const float* __restrict__ W,
    const float* __restrict__ coords, const float* __restrict__ rw,
    const float* __restrict__ mask,
    _Float16* __restrict__ xh, _Float16* __restrict__ Wt,
    _Float16* __restrict__ esch, _Float16* __restrict__ maskp) {
    __shared__ float smem[4352];        // 17.4 KB: prep_mask tile 64x68; transpose 32x33
    int bx = blockIdx.x, tid = threadIdx.x;
    if (bx < 2048) {
        // ---- convert x (fp32 -> fp16), 8 elements/thread ----
        int i = bx * 256 + tid;
        const floatx4* xin = (const floatx4*)x;
        floatx4 a = xin[i * 2];
        floatx4 b = xin[i * 2 + 1];
        half8 h;
        h[0] = (_Float16)a[0]; h[1] = (_Float16)a[1]; h[2] = (_Float16)a[2]; h[3] = (_Float16)a[3];
        h[4] = (_Float16)b[0]; h[5] = (_Float16)b[1]; h[6] = (_Float16)b[2]; h[7] = (_Float16)b[3];
        *(half8*)&xh[i * 8] = h;
    } else if (bx < 5120) {
        // ---- transpose + convert Wqkv [1024,3072] -> Wt fp16 [3072,1024] ----
        int b2 = bx - 2048;
        int n0 = (b2 % 96) * 32, k0 = (b2 / 96) * 32;
        int tx = tid & 31, ty = tid >> 5;   // (32,8)
        float (*tile)[33] = (float(*)[33])smem;
        #pragma unroll
        for (int r = 0; r < 4; ++r)
            tile[ty + r * 8][tx] = W[(size_t)(k0 + ty + r * 8) * 3072 + n0 + tx];
        __syncthreads();
        #pragma unroll
        for (int r = 0; r < 4; ++r)
            Wt[(size_t)(n0 + ty + r * 8) * 1024 + k0 + tx] = (_Float16)tile[tx][ty + r * 8];
    } else if (bx < 5376) {
        // ---- esch[b,h,n] = fp16( exp2(-LOG2E * sum_c coords*rw) ) ----
        int idx = (bx - 5120) * 256 + tid;
        int bh = idx >> 11, n = idx & 2047;
        int b = bh >> 4, h = bh & 15;
        const float* c = &coords[(b * 2048 + n) * 3];
        const float* w = &rw[h * 3];
        float v = -LOG2E * (c[0] * w[0] + c[1] * w[1] + c[2] * w[2]);
        esch[idx] = (_Float16)__builtin_amdgcn_exp2f(v);
    } else {
        // ---- mask -> fp16*LOG2E, S^T MFMA C-fragment layout ----
        int bid = bx - 5376;
        int qt = bid >> 5, kt = bid & 31;
        int row0 = qt * 64, col0 = kt * 64;
        int lr = tid >> 2, lc = (tid & 3) * 16;
        #pragma unroll
        for (int j = 0; j < 4; ++j)
            *(floatx4*)&smem[lr * 68 + lc + j * 4] =
                *(const floatx4*)&mask[(size_t)(row0 + lr) * 2048 + col0 + lc + j * 4];
        __syncthreads();
        int w = tid >> 6, lane = tid & 63, quad = lane >> 4, l16 = lane & 15;
        half4* outp = (half4*)maskp + (size_t)((qt * 32 + kt) * 4 + w) * 256 + lane;
        #pragma unroll
        for (int t = 0; t < 4; ++t) {
            floatx4 m = *(const floatx4*)&smem[(w * 16 + l16) * 68 + t * 16 + quad * 4];
            outp[t * 64] = pack4(m[0] * LOG2E, m[1] * LOG2E, m[2] * LOG2E, m[3] * LOG2E);
        }
    }
}

// ---------------- fused QKV GEMM: BK=32, double-buffered async staging ----------------
__global__ __launch_bounds__(256) void k_gemm(
    const _Float16* __restrict__ Ah, const _Float16* __restrict__ Bt,
    const float* __restrict__ bias, const _Float16* __restrict__ esch,
    _Float16* __restrict__ qh, _Float16* __restrict__ kh, _Float16* __restrict__ vt) {
    __shared__ _Float16 smem[16384];   // 2 bufs x (As 4096 + Bs 4096) halves = 32 KB
    int tid = threadIdx.x;
    int w = tid >> 6, lane = tid & 63;
    int quad = lane >> 4, l16 = lane & 15;
    int m0 = blockIdx.y * 128;
    int n0 = blockIdx.x * 128;
    bool QK = n0 < 2048;
    int mq = (w >> 1) * 64, nq = (w & 1) * 64;
    int c0 = n0 + nq;

    int rl4 = lane >> 2;            // row within 16-row staging chunk
    int pb4 = lane & 3;             // physical 16B block within 64B row
    floatx4 acc[4][4] = {};

    const _Float16* ap[2];
    const _Float16* bp[2];
    #pragma unroll
    for (int j = 0; j < 2; ++j) {
        int row = w * 32 + j * 16 + rl4;
        int lb = pb4 ^ (row & 3) ^ ((row >> 2) & 3);
        ap[j] = Ah + (size_t)(m0 + row) * 1024 + lb * 8;
        bp[j] = Bt + (size_t)(n0 + row) * 1024 + lb * 8;
    }

    #define GSTAGE(buf) {                                      \
        _Float16* As_ = smem + (buf) * 8192;                   \
        _Float16* Bs_ = As_ + 4096;                            \
        async16(ap[0], &As_[(w * 32) * 32]);                   \
        async16(ap[1], &As_[(w * 32 + 16) * 32]);              \
        async16(bp[0], &Bs_[(w * 32) * 32]);                   \
        async16(bp[1], &Bs_[(w * 32 + 16) * 32]);              \
        ap[0] += 32; ap[1] += 32; bp[0] += 32; bp[1] += 32;    \
    }

    #define GBODY(cur, last) {                                                         \
        __syncthreads();                                                               \
        if (!(last)) GSTAGE((cur) ^ 1);                                                \
        const _Float16* As_ = smem + (cur) * 8192;                                     \
        const _Float16* Bs_ = As_ + 4096;                                              \
        half8 af[4], bf[4];                                                            \
        _Pragma("unroll")                                                              \
        for (int s = 0; s < 4; ++s) {                                                  \
            int ra = mq + s * 16 + l16;                                                \
            af[s] = *(const half8*)&As_[ra * 32 +                                      \
                ((quad ^ (ra & 3) ^ ((ra >> 2) & 3)) << 3)];                           \
            int rb = nq + s * 16 + l16;                                                \
            bf[s] = *(const half8*)&Bs_[rb * 32 +                                      \
                ((quad ^ (rb & 3) ^ ((rb >> 2) & 3)) << 3)];                           \
        }                                                                              \
        if (QK) {                                                                      \
            _Pragma("unroll")                                                          \
            for (int ms = 0; ms < 4; ++ms)                                             \
                _Pragma("unroll")                                                      \
                for (int ns = 0; ns < 4; ++ns)                                         \
                    acc[ms][ns] = __builtin_amdgcn_mfma_f32_16x16x32_f16(              \
                        bf[ns], af[ms], acc[ms][ns], 0, 0, 0);                         \
        } else {                                                                       \
            _Pragma("unroll")                                                          \
            for (int ms = 0; ms < 4; ++ms)                                             \
                _Pragma("unroll")                                                      \
                for (int ns = 0; ns < 4; ++ns)                                         \
                    acc[ms][ns] = __builtin_amdgcn_mfma_f32_16x16x32_f16(              \
                        af[ms], bf[ns], acc[ms][ns], 0, 0, 0);                         \
        }                                                                              \
    }

    GSTAGE(0);
    #pragma unroll 1
    for (int kt2 = 0; kt2 < 15; ++kt2) {
        GBODY(0, false);
        GBODY(1, false);
    }
    GBODY(0, false);
    GBODY(1, true);
    #undef GBODY
    #undef GSTAGE

    __syncthreads();   // all waves done reading staging before slab reuse

    // ---- epilogue: wave-private 32x72 slab, 2 passes, coalesced half8 stores ----
    _Float16* Ls = smem + w * 2304;
    int rl = lane >> 3, pb = lane & 7;
    int b = (m0 + mq) >> 11, nbase = (m0 + mq) & 2047;
    if (QK) {
        float qsc = (c0 < 1024) ? QSCALE : 1.0f;    // q heads pre-scaled for softmax
        int h2 = c0 >> 6;                           // 0..31: q heads then k heads
        _Float16* dst = (h2 < 16 ? qh : kh) + (size_t)(((b << 4) + (h2 & 15)) * 2048) * 64;
        int d0 = pb << 3;
        #pragma unroll
        for (int p = 0; p < 2; ++p) {
            #pragma unroll
            for (int ns = 0; ns < 4; ++ns) {
                floatx4 b4 = *(const floatx4*)&bias[c0 + ns * 16 + quad * 4];
                #pragma unroll
                for (int m2 = 0; m2 < 2; ++m2) {
                    int ms = p * 2 + m2;
                    floatx4 v;
                    #pragma unroll
                    for (int i = 0; i < 4; ++i) v[i] = (acc[ms][ns][i] + b4[i]) * qsc;
                    *(half4*)&Ls[(m2 * 16 + l16) * 72 + ns * 16 + quad * 4] =
                        pack4(v[0], v[1], v[2], v[3]);
                }
            }
            #pragma unroll
            for (int rep = 0; rep < 4; ++rep) {
                int nl = rep * 8 + rl;
                half8 v = *(const half8*)&Ls[nl * 72 + d0];
                *(half8*)&dst[(size_t)(nbase + p * 32 + nl) * 64 + d0] = v;
            }
        }
    } else {
        int h = (c0 - 2048) >> 6;
        _Float16* dst = vt + (size_t)(((b << 4) + h) * 64) * 2048;
        // V rows scaled by e^{-cp[b,h,n]} in fp32 (single fp16 rounding, matched
        // bit-exactly with the attention denominator which uses the same fp16 esch).
        const _Float16* ePtr = esch + (size_t)((b << 4) + h) * 2048 + nbase + quad * 4;
        float ef[4][4];
        #pragma unroll
        for (int ms = 0; ms < 4; ++ms) {
            half4 e4 = *(const half4*)&ePtr[ms * 16];
            #pragma unroll
            for (int i = 0; i < 4; ++i) ef[ms][i] = (float)e4[i];
        }
        int noff = pb << 3;
        #pragma unroll
        for (int p = 0; p < 2; ++p) {
            #pragma unroll
            for (int n2 = 0; n2 < 2; ++n2) {
                int ns = p * 2 + n2;
                float bv = bias[c0 + ns * 16 + l16];
                #pragma unroll
                for (int ms = 0; ms < 4; ++ms) {
                    *(half4*)&Ls[(n2 * 16 + l16) * 72 + ms * 16 + quad * 4] =
                        pack4((acc[ms][ns][0] + bv) * ef[ms][0],
                              (acc[ms][ns][1] + bv) * ef[ms][1],
                              (acc[ms][ns][2] + bv) * ef[ms][2],
                              (acc[ms][ns][3] + bv) * ef[ms][3]);
                }
            }
            #pragma unroll
            for (int rep = 0; rep < 4; ++rep) {
                int cl = rep * 8 + rl;
                half8 v = *(const half8*)&Ls[cl * 72 + noff];
                *(half8*)&dst[(size_t)(p * 32 + cl) * 2048 + nbase + noff] = v;
            }
        }
    }
}

// ---------------- flash attention: in-block split-K, 8 waves, 32 q rows/wave ----------------
// R4: same split-K structure as R3 (verified correct), registers trimmed to fit the
// 128-VGPR / 4-waves-per-SIMD budget WITHOUT spills (R3's launch_bounds(512,4)
// empirically capped at 64 VGPR -> 157 MB scratch traffic):
//  - amdgpu_waves_per_eu(4) for the documented cap = 512/4 = 128
//  - mask prefetch single-set (reload same regs after QK phase), -16 VGPR
//  - esch staged once to a 4 KB LDS slab, broadcast ds_read per body, -8 VGPR
//  - K fragments per-t temporaries in a merged QK loop (both q-groups share), -24 peak
__global__ __launch_bounds__(512) __attribute__((amdgpu_waves_per_eu(4)))
void k_attn(
    const _Float16* __restrict__ qh, const _Float16* __restrict__ kh,
    const _Float16* __restrict__ vt, const _Float16* __restrict__ maskp,
    const _Float16* __restrict__ esch, float* __restrict__ out) {
    __shared__ _Float16 KV[2][2][8192];   // [group][buf]: K [0,4096), V [4096,8192); 64 KB
    __shared__ _Float16 es[2048];         // esch slice for this bh (4 KB)
    int tid = threadIdx.x;
    int w = tid >> 6, lane = tid & 63;
    int g2 = w >> 2, wg = w & 3;          // k-group, wave-within-group
    int quad = lane >> 4, l16 = lane & 15;
    int rl = lane >> 3, pb = lane & 7;
    int bid = blockIdx.x;
    int qt2 = bid & 15, bh = bid >> 4;
    int b = bh >> 4, h = bh & 15;
    int qrow = qt2 * 128 + wg * 32;

    // stage esch slice to LDS (visible after the first body's barrier)
    *(half4*)&es[tid * 4] = *(const half4*)&esch[(size_t)bh * 2048 + tid * 4];

    half8 qf[2][2];
    #pragma unroll
    for (int g = 0; g < 2; ++g) {
        const _Float16* qp = &qh[((size_t)bh * 2048 + qrow + g * 16 + l16) * 64];
        qf[g][0] = *(const half8*)&qp[quad * 8];
        qf[g][1] = *(const half8*)&qp[32 + quad * 8];
    }
    floatx4 o0[4] = {}, o1[4] = {};
    floatx4 ol0 = {}, ol1 = {};        // denominator accumulators (esch-weighted)

    int sw = (pb ^ rl) << 3;
    const _Float16* kp0 = kh + (size_t)bh * 131072 + (size_t)(wg * 16 + rl) * 64 + sw
                             + (size_t)g2 * 65536;
    const _Float16* kp1 = kp0 + 512;                 // +8 rows
    const _Float16* vp0 = vt + (size_t)bh * 131072 + (size_t)(wg * 16 + rl) * 2048 + sw
                             + (size_t)g2 * 1024;
    const _Float16* vp1 = vp0 + 16384;               // +8 d-rows
    // mask fragment pointers (old-fragment coords: qt_old = qt2*2 + (wg>>1),
    // w_old = (wg&1)*2 + g, starting k-tile = g2*16)
    const half4* mp0 = (const half4*)maskp +
        ((size_t)(qt2 * 2 + (wg >> 1)) * 128 + (size_t)g2 * 64 + (wg & 1) * 2) * 256 + lane;
    const half4* mp1 = mp0 + 256;
    int ecur = g2 * 1024 + quad * 4;      // LDS esch cursor

    // single-set mask prefetch registers (consumed at body top, reloaded mid-body)
    half4 mC0[4], mC1[4];

    #define STAGE(buf) {                                             \
        async16(kp0, &KV[g2][buf][(wg * 16) * 64]);                  \
        async16(kp1, &KV[g2][buf][(wg * 16 + 8) * 64]);              \
        async16(vp0, &KV[g2][buf][4096 + (wg * 16) * 64]);           \
        async16(vp1, &KV[g2][buf][4096 + (wg * 16 + 8) * 64]);       \
        kp0 += 4096; kp1 += 4096; vp0 += 64; vp1 += 64;              \
    }

    #define MPREF() {                                                \
        _Pragma("unroll")                                            \
        for (int t = 0; t < 4; ++t) mC0[t] = mp0[t * 64];            \
        _Pragma("unroll")                                            \
        for (int t = 0; t < 4; ++t) mC1[t] = mp1[t * 64];            \
        mp0 += 1024; mp1 += 1024;                                    \
    }

    #define BODY(cur, last) {                                                          \
        __syncthreads();                                                               \
        if (!(last)) STAGE((cur) ^ 1);                                                 \
        const _Float16* Ksc = &KV[g2][cur][0];                                         \
        const _Float16* Vsc = &KV[g2][cur][4096];                                      \
        half4 pt[2][4];                                                                \
        _Pragma("unroll")                                                              \
        for (int t = 0; t < 4; ++t) {                                                  \
            int r = t * 16 + l16;                                                      \
            half8 k0 = *(const half8*)&Ksc[r * 64 + ((quad ^ (r & 7)) << 3)];          \
            half8 k1 = *(const half8*)&Ksc[r * 64 + (((quad + 4) ^ (r & 7)) << 3)];    \
            {                                                                          \
                half4 ml = mC0[t];                                                     \
                floatx4 z;                                                             \
                z[0] = (float)ml[0]; z[1] = (float)ml[1];                              \
                z[2] = (float)ml[2]; z[3] = (float)ml[3];                              \
                z = __builtin_amdgcn_mfma_f32_16x16x32_f16(k0, qf[0][0], z, 0, 0, 0);  \
                z = __builtin_amdgcn_mfma_f32_16x16x32_f16(k1, qf[0][1], z, 0, 0, 0);  \
                pt[0][t] = pack4(__builtin_amdgcn_exp2f(z[0]),                         \
                                 __builtin_amdgcn_exp2f(z[1]),                         \
                                 __builtin_amdgcn_exp2f(z[2]),                         \
                                 __builtin_amdgcn_exp2f(z[3]));                        \
            }                                                                          \
            {                                                                          \
                half4 ml = mC1[t];                                                     \
                floatx4 z;                                                             \
                z[0] = (float)ml[0]; z[1] = (float)ml[1];                              \
                z[2] = (float)ml[2]; z[3] = (float)ml[3];                              \
                z = __builtin_amdgcn_mfma_f32_16x16x32_f16(k0, qf[1][0], z, 0, 0, 0);  \
                z = __builtin_amdgcn_mfma_f32_16x16x32_f16(k1, qf[1][1], z, 0, 0, 0);  \
                pt[1][t] = pack4(__builtin_amdgcn_exp2f(z[0]),                         \
                                 __builtin_amdgcn_exp2f(z[1]),                         \
                                 __builtin_amdgcn_exp2f(z[2]),                         \
                                 __builtin_amdgcn_exp2f(z[3]));                        \
            }                                                                          \
        }                                                                              \
        if (!(last)) MPREF();                                                          \
        _Pragma("unroll")                                                              \
        for (int t = 0; t < 4; ++t) {                                                  \
            half4 ev = *(const half4*)&es[ecur + t * 16];                              \
            ol0 = __builtin_amdgcn_mfma_f32_16x16x16f16(ev, pt[0][t], ol0, 0, 0, 0);   \
            ol1 = __builtin_amdgcn_mfma_f32_16x16x16f16(ev, pt[1][t], ol1, 0, 0, 0);   \
        }                                                                              \
        ecur += 64;                                                                    \
        _Pragma("unroll")                                                              \
        for (int dt = 0; dt < 4; ++dt) {                                               \
            int rv = dt * 16 + l16;                                                    \
            _Pragma("unroll")                                                          \
            for (int t = 0; t < 4; ++t) {                                              \
                half4 vf = *(const half4*)&Vsc[rv * 64 +                               \
                    (((t * 2 + (quad >> 1)) ^ (rv & 7)) << 3) + ((quad & 1) << 2)];    \
                o0[dt] = __builtin_amdgcn_mfma_f32_16x16x16f16(vf, pt[0][t], o0[dt], 0, 0, 0); \
                o1[dt] = __builtin_amdgcn_mfma_f32_16x16x16f16(vf, pt[1][t], o1[dt], 0, 0, 0); \
            }                                                                          \
        }                                                                              \
    }

    STAGE(0);
    MPREF();
    #pragma unroll 1
    for (int kt2 = 0; kt2 < 7; ++kt2) {
        BODY(0, false);
        BODY(1, false);
    }
    BODY(0, false);
    BODY(1, true);
    #undef BODY
    #undef MPREF
    #undef STAGE

    // ---- combine partials across the wave pair (w, w^4) via LDS ----
    __syncthreads();                       // everyone done reading staging buffers
    float* comb = (float*)KV;              // 8 waves x 17 idx x 64 lanes = 34.8 KB
    {
        float* dst = comb + ((size_t)w * 17) * 64 + lane;
        if (g2 == 0) {                     // group 0 exports o1/ol1 (partner stores rows +16)
            #pragma unroll
            for (int dt = 0; dt < 4; ++dt)
                #pragma unroll
                for (int i = 0; i < 4; ++i)
                    dst[(dt * 4 + i) * 64] = o1[dt][i];
            dst[16 * 64] = ol1[0];
        } else {                           // group 1 exports o0/ol0
            #pragma unroll
            for (int dt = 0; dt < 4; ++dt)
                #pragma unroll
                for (int i = 0; i < 4; ++i)
                    dst[(dt * 4 + i) * 64] = o0[dt][i];
            dst[16 * 64] = ol0[0];
        }
    }
    __syncthreads();
    {
        const float* src = comb + ((size_t)(w ^ 4) * 17) * 64 + lane;
        if (g2 == 0) {
            // sum own o0 with partner's o0 -> store q-group 0 (rows qrow + l16)
            #pragma unroll
            for (int dt = 0; dt < 4; ++dt)
                #pragma unroll
                for (int i = 0; i < 4; ++i)
                    o0[dt][i] += src[(dt * 4 + i) * 64];
            float inv = 1.f / (ol0[0] + src[16 * 64]);
            size_t obase = ((size_t)(b * 2048 + qrow + l16)) * 1024 + h * 64 + quad * 4;
            #pragma unroll
            for (int dt = 0; dt < 4; ++dt) {
                floatx4 r;
                #pragma unroll
                for (int i = 0; i < 4; ++i) r[i] = o0[dt][i] * inv;
                *(floatx4*)&out[obase + dt * 16] = r;
            }
        } else {
            // sum own o1 with partner's o1 -> store q-group 1 (rows qrow + 16 + l16)
            #pragma unroll
            for (int dt = 0; dt < 4; ++dt)
                #pragma unroll
                for (int i = 0; i < 4; ++i)
                    o1[dt][i] += src[(dt * 4 + i) * 64];
            float inv = 1.f / (ol1[0] + src[16 * 64]);
            size_t obase = ((size_t)(b * 2048 + qrow + 16 + l16)) * 1024 + h * 64 + quad * 4;
            #pragma unroll
            for (int dt = 0; dt < 4; ++dt) {
                floatx4 r;
                #pragma unroll
                for (int i = 0; i < 4; ++i) r[i] = o1[dt][i] * inv;
                *(floatx4*)&out[obase + dt * 16] = r;
            }
        }
    }
}

extern "C" void kernel_launch(void* const* d_in, const int* in_sizes, int n_in,
                              void* d_out, int out_size, void* d_ws, size_t ws_size,
                              hipStream_t stream) {
    const float* x      = (const float*)d_in[0];
    const float* coords = (const float*)d_in[1];
    const float* mask   = (const float*)d_in[2];
    const float* Wqkv   = (const float*)d_in[3];
    const float* bqkv   = (const float*)d_in[4];
    const float* rw     = (const float*)d_in[5];
    float* out = (float*)d_out;

    // Workspace layout
    //   xh   : [0,          8,388,608)
    //   maskp: [8,388,608,  16,777,216)
    //   Wt   : [16,777,216, 23,068,672)
    //   qh   : [23,068,672, 31,457,280)
    //   kh   : [31,457,280, 39,845,888)
    //   vt   : [39,845,888, 48,234,496)
    //   esch : [48,234,496, 48,365,568)
    char* ws = (char*)d_ws;
    _Float16* xh    = (_Float16*)(ws);
    _Float16* maskp = (_Float16*)(ws + 8388608);
    _Float16* Wt    = (_Float16*)(ws + 16777216);
    _Float16* qh    = (_Float16*)(ws + 23068672);
    _Float16* kh    = (_Float16*)(ws + 31457280);
    _Float16* vt    = (_Float16*)(ws + 39845888);
    _Float16* esch  = (_Float16*)(ws + 48234496);

    k_prep<<<6400, 256, 0, stream>>>(x, Wqkv, coords, rw, mask, xh, Wt, esch, maskp);
    k_gemm<<<dim3(24, 32), 256, 0, stream>>>(xh, Wt, bqkv, esch, qh, kh, vt);
    k_attn<<<512, 512, 0, stream>>>(qh, kh, vt, maskp, esch, out);
}